// Round 18
// baseline (157.849 us; speedup 1.0000x reference)
//
#include <hip/hip_runtime.h>
#include <hip/hip_bf16.h>
#include <stdint.h>

#define B_  8
#define T_  2048
#define D_  768
#define HD_ 64
#define M_  (B_ * T_)   // 16384
#define NBLK 512

typedef short s16x8 __attribute__((ext_vector_type(8)));
typedef float f32x4 __attribute__((ext_vector_type(4)));
typedef float f32x16 __attribute__((ext_vector_type(16)));
typedef unsigned int u32;

union Frag { uint4 u; s16x8 h; };

__device__ __forceinline__ unsigned short f2bf(float f) {
    unsigned u = __builtin_bit_cast(unsigned, f);
    u += 0x7FFFu + ((u >> 16) & 1u);            // RNE
    return (unsigned short)(u >> 16);
}
__device__ __forceinline__ unsigned pack_bf16x2(float lo, float hi) {
    return (unsigned)f2bf(lo) | ((unsigned)f2bf(hi) << 16);
}
// single-instruction packed f32x2 -> bf16x2 (RNE), gfx950
__device__ __forceinline__ unsigned cvt_pk(float lo, float hi) {
    unsigned r;
    asm("v_cvt_pk_bf16_f32 %0, %1, %2" : "=v"(r) : "v"(lo), "v"(hi));
    return r;
}

// async global -> LDS, 16B/lane; LDS dest must be the WAVE-UNIFORM base
// (hardware adds lane*16); global src is per-lane.
__device__ __forceinline__ void gl_lds16(const void* g, void* l) {
    __builtin_amdgcn_global_load_lds(
        (const __attribute__((address_space(1))) u32*)g,
        (__attribute__((address_space(3))) u32*)l, 16, 0, 0);
}

// Manual grid barrier.  Safe because all NBLK blocks are co-resident by
// construction: 64KB LDS (2 fit in 160KB), VGPR<=256 (launch_bounds cap)
// -> 8 waves/CU <= 32 -> exactly 2 blocks/CU x 256 CUs = 512.
// Release: threadfence (L2 writeback) before arrive; acquire: threadfence
// (L1/L2 invalidate) after spin -> cross-XCD visibility incl. poisoned lines.
__device__ __forceinline__ void grid_barrier(unsigned* cnt) {
    __syncthreads();
    if (threadIdx.x == 0) {
        __threadfence();                                   // release
        __hip_atomic_fetch_add(cnt, 1u, __ATOMIC_ACQ_REL, __HIP_MEMORY_SCOPE_AGENT);
        while (__hip_atomic_load(cnt, __ATOMIC_ACQUIRE, __HIP_MEMORY_SCOPE_AGENT) < (unsigned)NBLK)
            __builtin_amdgcn_s_sleep(2);
        __threadfence();                                   // acquire
    }
    __syncthreads();
}

// ---------------------------------------------------------------------------
// ONE kernel, 512 blocks x 256 thr, 2 blocks/CU co-resident (by arithmetic).
// Phase 0 (blocks 0..71): pack W into MFMA B-frag order.
// grid_barrier
// Phase 1: QKV projection (r15 body: BM=32, 4-buf swizzled DMA, 3-set B
//          rotation, single barrier/phase, waits 10/16/../8/0).
// grid_barrier
// Phase 2: causal flash attention (r15 body: QBLK=32, 4-way K-split,
//          wave-private LDS, pairwise barrier-free loop 12/4/0, parallel
//          4-way merge epilogue).
// ---------------------------------------------------------------------------
__global__ __launch_bounds__(256, 2) void fused(const float* __restrict__ x,
                                                const float* __restrict__ Wq,
                                                const float* __restrict__ Wk,
                                                const float* __restrict__ Wv,
                                                unsigned short* __restrict__ pk,
                                                unsigned short* __restrict__ qo,
                                                unsigned short* __restrict__ ko,
                                                unsigned short* __restrict__ vt,
                                                float* __restrict__ out,
                                                unsigned* __restrict__ cnt) {
    __shared__ char smem[65536];
    int tid = threadIdx.x, blk = blockIdx.x;

    // ================= Phase 0: prep (blocks 0..71 busy) ===================
    {
        int id = blk * 256 + tid;
        if (id < 288 * 64) {
            int tile = id >> 6, lane = id & 63;
            int nb = tile / 24, kk = tile % 24;
            int g = lane >> 4, t = lane & 15;
            int mat = nb >> 2, col = (nb & 3) * 16 + t;
            const float* W = (mat == 0) ? Wq : (mat == 1) ? Wk : Wv;
            float s = (mat == 0) ? 0.18033688011112042f : 1.0f;  // 0.125*log2e
            float v[8];
#pragma unroll
            for (int e = 0; e < 8; e++)
                v[e] = W[(size_t)(kk * 32 + g * 8 + e) * HD_ + col] * s;
            uint4 u;
            u.x = pack_bf16x2(v[0], v[1]);
            u.y = pack_bf16x2(v[2], v[3]);
            u.z = pack_bf16x2(v[4], v[5]);
            u.w = pack_bf16x2(v[6], v[7]);
            *(uint4*)(pk + ((size_t)tile * 64 + lane) * 8) = u;
        }
    }
    grid_barrier(cnt);

    // ================= Phase 1: QKV projection =============================
    {
        char (*xs)[8192] = (char(*)[8192])smem;   // [4][32 rows][16 slots]

        int w = tid >> 6, lane = tid & 63;
        int g = lane >> 4, t = lane & 15;
        int m0 = blk * 32;

        auto STAGE = [&](int jb) {
            int buf = jb & 3;
#pragma unroll
            for (int h = 0; h < 2; h++) {
                int s = tid + h * 256;                 // slot 0..511
                int row = s >> 4;
                int a = (s & 15) ^ (row & 15);
                gl_lds16(x + (size_t)(m0 + row) * D_ + jb * 64 + a * 4,
                         &xs[buf][(w * 64 + h * 256) * 16]);
            }
        };

        const unsigned short* wp = pk + (size_t)w * 36864;   // wave's 3 nb-blocks
        auto LOADB = [&](Frag (&bb)[6], int jb) {
#pragma unroll
            for (int j = 0; j < 3; j++)
#pragma unroll
                for (int c = 0; c < 2; c++)
                    bb[j * 2 + c].u = *(const uint4*)(wp + ((size_t)(j * 24 + jb * 2 + c) * 64 + lane) * 8);
        };

        f32x4 acc[3][2];
#pragma unroll
        for (int j = 0; j < 3; j++)
#pragma unroll
            for (int mf = 0; mf < 2; mf++) acc[j][mf] = (f32x4){0.f, 0.f, 0.f, 0.f};

        Frag bfr[3][6];
        LOADB(bfr[0], 0);
        LOADB(bfr[1], 1);
        STAGE(0); STAGE(1); STAGE(2);

#pragma unroll
        for (int jb = 0; jb < 12; jb++) {
            if (jb + 2 < 12) LOADB(bfr[(jb + 2) % 3], jb + 2);
            if (jb == 0)       asm volatile("s_waitcnt vmcnt(10)" ::: "memory");
            else if (jb == 10) asm volatile("s_waitcnt vmcnt(8)"  ::: "memory");
            else if (jb == 11) asm volatile("s_waitcnt vmcnt(0)"  ::: "memory");
            else               asm volatile("s_waitcnt vmcnt(16)" ::: "memory");
            __builtin_amdgcn_s_barrier();
            if (jb + 3 < 12) STAGE(jb + 3);    // target buf dead since jb-1
            int buf = jb & 3;

            Frag af[2][2];
#pragma unroll
            for (int mf = 0; mf < 2; mf++) {
                int r32 = mf * 16 + t;
#pragma unroll
                for (int c = 0; c < 2; c++) {
                    float4 f0 = *(const float4*)(&xs[buf][r32 * 256 + (((c * 8 + g * 2 + 0) ^ t) * 16)]);
                    float4 f1 = *(const float4*)(&xs[buf][r32 * 256 + (((c * 8 + g * 2 + 1) ^ t) * 16)]);
                    af[mf][c].u.x = cvt_pk(f0.x, f0.y);
                    af[mf][c].u.y = cvt_pk(f0.z, f0.w);
                    af[mf][c].u.z = cvt_pk(f1.x, f1.y);
                    af[mf][c].u.w = cvt_pk(f1.z, f1.w);
                }
            }
            __builtin_amdgcn_s_setprio(1);
#pragma unroll
            for (int j = 0; j < 3; j++)
#pragma unroll
                for (int c = 0; c < 2; c++) {
                    acc[j][0] = __builtin_amdgcn_mfma_f32_16x16x32_bf16(af[0][c].h, bfr[jb % 3][j * 2 + c].h, acc[j][0], 0, 0, 0);
                    acc[j][1] = __builtin_amdgcn_mfma_f32_16x16x32_bf16(af[1][c].h, bfr[jb % 3][j * 2 + c].h, acc[j][1], 0, 0, 0);
                }
            __builtin_amdgcn_s_setprio(0);
        }

#pragma unroll
        for (int j = 0; j < 3; j++) {
            int nb = w * 3 + j;
            int col = (nb & 3) * 16 + t;
#pragma unroll
            for (int mf = 0; mf < 2; mf++) {
                int row0 = m0 + mf * 16;
                if (nb < 8) {
                    unsigned short* dst = (nb < 4) ? qo : ko;
#pragma unroll
                    for (int r = 0; r < 4; r++)
                        dst[(size_t)(row0 + g * 4 + r) * HD_ + col] = f2bf(acc[j][mf][r]);
                } else {
                    int bb = m0 >> 11;
                    int trow = (row0 & 2047) + g * 4;
                    uint2 pkk;
                    pkk.x = cvt_pk(acc[j][mf][0], acc[j][mf][1]);
                    pkk.y = cvt_pk(acc[j][mf][2], acc[j][mf][3]);
                    *(uint2*)(vt + (((size_t)(bb * HD_ + col)) << 11) + trow) = pkk;
                }
            }
        }
    }
    grid_barrier(cnt + 16);

    // ================= Phase 2: causal flash attention =====================
    {
        int wv = tid >> 6, lane = tid & 63;
        int hi = lane >> 5, l31 = lane & 31;
        int b = blk & 7, idx = blk >> 3;                     // idx 0..63
        int qblk = (idx < 32) ? (63 - idx) : (idx - 32);     // heavy first
        int q0 = qblk * 32;
        int qg = q0 + l31;                                   // this lane's q row
        size_t bbase = (size_t)b * T_;
        int nt = qblk + 1;                                   // 32-key tiles
        int ks = wv;                                         // K-split
        int mt = (nt > ks) ? ((nt - ks + 3) >> 2) : 0;       // tiles for wave

        const unsigned short* kp = ko + bbase * HD_;
        const unsigned short* vp = vt + ((size_t)(b * HD_) << 11);
        char* KV = smem + wv * 16384;                        // wave-private

        Frag qf[4];
#pragma unroll
        for (int c = 0; c < 4; c++)
            qf[c].u = *(const uint4*)(qo + (bbase + qg) * HD_ + c * 16 + hi * 8);

        auto STAGE = [&](int j, int buf) {   // 4 K-chunks THEN 4 V-chunks
            int jj = (j < nt) ? j : (nt - 1);
            int kv0 = jj * 32;
#pragma unroll
            for (int q = 0; q < 4; q++) {    // K tile [32 keys][8 slots], ^= row&7
                int kr = q * 8 + (lane >> 3);
                int ka = (lane & 7) ^ (kr & 7);
                gl_lds16(kp + (size_t)(kv0 + kr) * HD_ + ka * 8, KV + buf * 4096 + q * 1024);
            }
#pragma unroll
            for (int q = 0; q < 4; q++) {    // V^T tile [64 d][4 slots], 3-term swz
                int vd = q * 16 + (lane >> 2);
                int va = (lane & 3) ^ (vd & 3) ^ ((vd >> 2) & 3);
                gl_lds16(vp + ((size_t)vd << 11) + kv0 + va * 8, KV + 8192 + buf * 4096 + q * 1024);
            }
        };

        f32x16 o0, o1;
#pragma unroll
        for (int r = 0; r < 16; r++) { o0[r] = 0.f; o1[r] = 0.f; }
        float lacc = 0.f;

        auto QK = [&](const char* KB, f32x16& st) {
#pragma unroll
            for (int r = 0; r < 16; r++) st[r] = 0.f;
            __builtin_amdgcn_s_setprio(1);
#pragma unroll
            for (int c = 0; c < 4; c++) {
                Frag ka;
                ka.u = *(const uint4*)(KB + l31 * 128 + (((c * 2 + hi) ^ (l31 & 7)) * 16));
                st = __builtin_amdgcn_mfma_f32_32x32x16_bf16(ka.h, qf[c].h, st, 0, 0, 0);
            }
            __builtin_amdgcn_s_setprio(0);
        };

        auto SMPV = [&](f32x16& st, int j, const char* VB) {
            int kv0 = j * 32;
            if (j == qblk) {           // diagonal tile: causal mask
#pragma unroll
                for (int r = 0; r < 16; r++) {
                    int key = kv0 + (r & 3) + 8 * (r >> 2) + 4 * hi;
                    if (key > qg) st[r] = -1e30f;
                }
            }
            float p[16], ss = 0.f;
#pragma unroll
            for (int r = 0; r < 16; r++) { p[r] = exp2f(st[r]); ss += p[r]; }
            lacc += ss;

            u32 A0 = cvt_pk(p[0], p[1]),   A1 = cvt_pk(p[2], p[3]);
            u32 B0 = cvt_pk(p[4], p[5]),   B1 = cvt_pk(p[6], p[7]);
            u32 C0 = cvt_pk(p[8], p[9]),   C1 = cvt_pk(p[10], p[11]);
            u32 D0 = cvt_pk(p[12], p[13]), D1 = cvt_pk(p[14], p[15]);
            u32 A0x = (u32)__shfl_xor((int)A0, 32);
            u32 A1x = (u32)__shfl_xor((int)A1, 32);
            u32 B0x = (u32)__shfl_xor((int)B0, 32);
            u32 B1x = (u32)__shfl_xor((int)B1, 32);
            u32 C0x = (u32)__shfl_xor((int)C0, 32);
            u32 C1x = (u32)__shfl_xor((int)C1, 32);
            u32 D0x = (u32)__shfl_xor((int)D0, 32);
            u32 D1x = (u32)__shfl_xor((int)D1, 32);
            Frag pf0, pf1;
            pf0.u.x = hi ? B0x : A0;
            pf0.u.y = hi ? B1x : A1;
            pf0.u.z = hi ? B0  : A0x;
            pf0.u.w = hi ? B1  : A1x;
            pf1.u.x = hi ? D0x : C0;
            pf1.u.y = hi ? D1x : C1;
            pf1.u.z = hi ? D0  : C0x;
            pf1.u.w = hi ? D1  : C1x;

            __builtin_amdgcn_s_setprio(1);
            {
                int sw0 = (l31 & 3) ^ ((l31 >> 2) & 3);
                Frag va;
                va.u = *(const uint4*)(VB + l31 * 64 + (((hi) ^ sw0) * 16));
                o0 = __builtin_amdgcn_mfma_f32_32x32x16_bf16(va.h, pf0.h, o0, 0, 0, 0);
                va.u = *(const uint4*)(VB + l31 * 64 + (((2 + hi) ^ sw0) * 16));
                o0 = __builtin_amdgcn_mfma_f32_32x32x16_bf16(va.h, pf1.h, o0, 0, 0, 0);
                int d1 = 32 + l31;
                int sw1 = (d1 & 3) ^ ((d1 >> 2) & 3);
                va.u = *(const uint4*)(VB + d1 * 64 + (((hi) ^ sw1) * 16));
                o1 = __builtin_amdgcn_mfma_f32_32x32x16_bf16(va.h, pf0.h, o1, 0, 0, 0);
                va.u = *(const uint4*)(VB + d1 * 64 + (((2 + hi) ^ sw1) * 16));
                o1 = __builtin_amdgcn_mfma_f32_32x32x16_bf16(va.h, pf1.h, o1, 0, 0, 0);
            }
            __builtin_amdgcn_s_setprio(0);
        };

        if (mt > 0) STAGE(ks, 0);
        if (mt > 1) STAGE(ks + 4, 1);

        int i = 0;
#pragma unroll 1
        for (; i + 2 <= mt; i += 2) {
            int ja = ks + 4 * i, jb2 = ja + 4;
            const char* KA = KV + (i & 1) * 4096;
            const char* VA = KV + 8192 + (i & 1) * 4096;
            const char* KB2 = KV + ((i + 1) & 1) * 4096;
            const char* VB2 = KV + 8192 + ((i + 1) & 1) * 4096;

            asm volatile("s_waitcnt vmcnt(12)" ::: "memory");   // K(a) ready
            f32x16 sa;
            QK(KA, sa);
            asm volatile("s_waitcnt vmcnt(4)" ::: "memory");    // V(a), K(b) ready
            f32x16 sb;
            QK(KB2, sb);          // overlaps softmax(a) (independent pipes)
            SMPV(sa, ja, VA);
            asm volatile("s_waitcnt vmcnt(0)" ::: "memory");    // V(b) ready
            if (i + 2 < mt) STAGE(ks + 4 * (i + 2), i & 1);
            SMPV(sb, jb2, VB2);
            if (i + 3 < mt) STAGE(ks + 4 * (i + 3), (i + 1) & 1);
        }
        if (i < mt) {   // odd tail: single tile, 8 outstanding at entry
            int ja = ks + 4 * i;
            const char* KA = KV + (i & 1) * 4096;
            const char* VA = KV + 8192 + (i & 1) * 4096;
            asm volatile("s_waitcnt vmcnt(4)" ::: "memory");    // K ready
            f32x16 sa;
            QK(KA, sa);
            asm volatile("s_waitcnt vmcnt(0)" ::: "memory");    // V ready
            SMPV(sa, ja, VA);
        }

        asm volatile("s_waitcnt vmcnt(0)" ::: "memory");   // drain before LDS reuse
        lacc += __shfl_xor(lacc, 32);
        __syncthreads();   // all waves done

        // ---- parallel 4-way merge ----
        float* MO = (float*)smem;
        {
            int base = (wv * 64 + lane) * 36;
#pragma unroll
            for (int qd = 0; qd < 4; qd++) {
                float4 w4;
                w4.x = o0[qd * 4 + 0]; w4.y = o0[qd * 4 + 1];
                w4.z = o0[qd * 4 + 2]; w4.w = o0[qd * 4 + 3];
                *(float4*)&MO[base + qd * 4] = w4;
                float4 v4;
                v4.x = o1[qd * 4 + 0]; v4.y = o1[qd * 4 + 1];
                v4.z = o1[qd * 4 + 2]; v4.w = o1[qd * 4 + 3];
                *(float4*)&MO[base + 16 + qd * 4] = v4;
            }
            MO[base + 32] = lacc;
        }
        __syncthreads();
        {
            int row = tid >> 3;                    // 0..31
            int c0 = (tid & 7) * 8;                // col base (multiple of 8)
            int j0 = 4 * ((c0 & 31) >> 3) + ((c0 >> 5) << 4);
            float lsum = 0.f;
#pragma unroll
            for (int k = 0; k < 4; k++) lsum += MO[(k * 64 + row) * 36 + 32];
            float inv = 1.0f / lsum;
            float4 aq = {0.f, 0.f, 0.f, 0.f};
            float4 bq = {0.f, 0.f, 0.f, 0.f};
#pragma unroll
            for (int k = 0; k < 4; k++) {
                float4 v0 = *(const float4*)&MO[(k * 64 + row) * 36 + j0];
                float4 v1 = *(const float4*)&MO[(k * 64 + row + 32) * 36 + j0];
                aq.x += v0.x; aq.y += v0.y; aq.z += v0.z; aq.w += v0.w;
                bq.x += v1.x; bq.y += v1.y; bq.z += v1.z; bq.w += v1.w;
            }
            aq.x *= inv; aq.y *= inv; aq.z *= inv; aq.w *= inv;
            bq.x *= inv; bq.y *= inv; bq.z *= inv; bq.w *= inv;
            float* op = out + (bbase + q0 + row) * HD_ + c0;
            *(float4*)&op[0] = aq;
            *(float4*)&op[4] = bq;
        }
    }
}

// ---------------------------------------------------------------------------
extern "C" void kernel_launch(void* const* d_in, const int* in_sizes, int n_in,
                              void* d_out, int out_size, void* d_ws, size_t ws_size,
                              hipStream_t stream) {
    const float* x  = (const float*)d_in[0];
    const float* Wq = (const float*)d_in[1];
    const float* Wk = (const float*)d_in[2];
    const float* Wv = (const float*)d_in[3];
    char* ws = (char*)d_ws;
    unsigned short* pkw = (unsigned short*)ws;                        // 294912 B
    unsigned short* qw = (unsigned short*)(ws + 294912);              // 2 MB
    unsigned short* kw = (unsigned short*)(ws + 294912 + 2097152);    // 2 MB
    unsigned short* vt = (unsigned short*)(ws + 294912 + 4194304);    // 2 MB
    unsigned* cnt = (unsigned*)(ws + 294912 + 6291456);               // 2 counters (128B)
    float* out = (float*)d_out;

    hipMemsetAsync(cnt, 0, 128, stream);
    hipLaunchKernelGGL(fused, dim3(NBLK), dim3(256), 0, stream,
                       x, Wq, Wk, Wv, pkw, qw, kw, vt, out, cnt);
}

// Round 19
// 127.318 us; speedup vs baseline: 1.2398x; 1.2398x over previous
//
#include <hip/hip_runtime.h>
#include <hip/hip_bf16.h>
#include <stdint.h>

#define B_  8
#define T_  2048
#define D_  768
#define HD_ 64
#define M_  (B_ * T_)   // 16384
#define NBLK 512

typedef short s16x8 __attribute__((ext_vector_type(8)));
typedef float f32x4 __attribute__((ext_vector_type(4)));
typedef float f32x16 __attribute__((ext_vector_type(16)));
typedef unsigned int u32;

union Frag { uint4 u; s16x8 h; };

__device__ __forceinline__ unsigned short f2bf(float f) {
    unsigned u = __builtin_bit_cast(unsigned, f);
    u += 0x7FFFu + ((u >> 16) & 1u);            // RNE
    return (unsigned short)(u >> 16);
}
__device__ __forceinline__ unsigned pack_bf16x2(float lo, float hi) {
    return (unsigned)f2bf(lo) | ((unsigned)f2bf(hi) << 16);
}
// single-instruction packed f32x2 -> bf16x2 (RNE), gfx950
__device__ __forceinline__ unsigned cvt_pk(float lo, float hi) {
    unsigned r;
    asm("v_cvt_pk_bf16_f32 %0, %1, %2" : "=v"(r) : "v"(lo), "v"(hi));
    return r;
}

// async global -> LDS, 16B/lane; LDS dest must be the WAVE-UNIFORM base
// (hardware adds lane*16); global src is per-lane.
__device__ __forceinline__ void gl_lds16(const void* g, void* l) {
    __builtin_amdgcn_global_load_lds(
        (const __attribute__((address_space(1))) u32*)g,
        (__attribute__((address_space(3))) u32*)l, 16, 0, 0);
}

// Manual grid barrier, RELAXED spin (r19 fix).  r18's ACQUIRE-per-poll
// emitted buffer_inv (L1+L2 invalidate) on every poll -> invalidation storm.
// Here: one release fence (wbL2) before arrive, RELAXED polls (read via L3,
// no invalidation), one acquire fence (inv) after exit.  Co-residency of all
// 512 blocks is by arithmetic: 64KB LDS (2/CU of 160KB), VGPR<=128 -> 2
// blocks/CU x 256 CU = 512.
__device__ __forceinline__ void grid_barrier(unsigned* cnt) {
    __syncthreads();
    if (threadIdx.x == 0) {
        __threadfence();                                   // release: wbL2
        __hip_atomic_fetch_add(cnt, 1u, __ATOMIC_RELAXED, __HIP_MEMORY_SCOPE_AGENT);
        while (__hip_atomic_load(cnt, __ATOMIC_RELAXED, __HIP_MEMORY_SCOPE_AGENT) < (unsigned)NBLK)
            __builtin_amdgcn_s_sleep(8);
        __threadfence();                                   // acquire: inv (once)
    }
    __syncthreads();
}

// ---------------------------------------------------------------------------
// ONE kernel, 512 blocks x 256 thr, 2 blocks/CU co-resident.
// Phase 0 (blocks 0..71): pack W into MFMA B-frag order.
// grid_barrier
// Phase 1: QKV projection (r15 body).
// grid_barrier
// Phase 2: causal flash attention (r15 body).
// ---------------------------------------------------------------------------
__global__ __launch_bounds__(256, 2) void fused(const float* __restrict__ x,
                                                const float* __restrict__ Wq,
                                                const float* __restrict__ Wk,
                                                const float* __restrict__ Wv,
                                                unsigned short* __restrict__ pk,
                                                unsigned short* __restrict__ qo,
                                                unsigned short* __restrict__ ko,
                                                unsigned short* __restrict__ vt,
                                                float* __restrict__ out,
                                                unsigned* __restrict__ cnt) {
    __shared__ char smem[65536];
    int tid = threadIdx.x, blk = blockIdx.x;

    // ================= Phase 0: prep (blocks 0..71 busy) ===================
    {
        int id = blk * 256 + tid;
        if (id < 288 * 64) {
            int tile = id >> 6, lane = id & 63;
            int nb = tile / 24, kk = tile % 24;
            int g = lane >> 4, t = lane & 15;
            int mat = nb >> 2, col = (nb & 3) * 16 + t;
            const float* W = (mat == 0) ? Wq : (mat == 1) ? Wk : Wv;
            float s = (mat == 0) ? 0.18033688011112042f : 1.0f;  // 0.125*log2e
            float v[8];
#pragma unroll
            for (int e = 0; e < 8; e++)
                v[e] = W[(size_t)(kk * 32 + g * 8 + e) * HD_ + col] * s;
            uint4 u;
            u.x = pack_bf16x2(v[0], v[1]);
            u.y = pack_bf16x2(v[2], v[3]);
            u.z = pack_bf16x2(v[4], v[5]);
            u.w = pack_bf16x2(v[6], v[7]);
            *(uint4*)(pk + ((size_t)tile * 64 + lane) * 8) = u;
        }
    }
    grid_barrier(cnt);

    // ================= Phase 1: QKV projection =============================
    {
        char (*xs)[8192] = (char(*)[8192])smem;   // [4][32 rows][16 slots]

        int w = tid >> 6, lane = tid & 63;
        int g = lane >> 4, t = lane & 15;
        int m0 = blk * 32;

        auto STAGE = [&](int jb) {
            int buf = jb & 3;
#pragma unroll
            for (int h = 0; h < 2; h++) {
                int s = tid + h * 256;                 // slot 0..511
                int row = s >> 4;
                int a = (s & 15) ^ (row & 15);
                gl_lds16(x + (size_t)(m0 + row) * D_ + jb * 64 + a * 4,
                         &xs[buf][(w * 64 + h * 256) * 16]);
            }
        };

        const unsigned short* wp = pk + (size_t)w * 36864;   // wave's 3 nb-blocks
        auto LOADB = [&](Frag (&bb)[6], int jb) {
#pragma unroll
            for (int j = 0; j < 3; j++)
#pragma unroll
                for (int c = 0; c < 2; c++)
                    bb[j * 2 + c].u = *(const uint4*)(wp + ((size_t)(j * 24 + jb * 2 + c) * 64 + lane) * 8);
        };

        f32x4 acc[3][2];
#pragma unroll
        for (int j = 0; j < 3; j++)
#pragma unroll
            for (int mf = 0; mf < 2; mf++) acc[j][mf] = (f32x4){0.f, 0.f, 0.f, 0.f};

        Frag bfr[3][6];
        LOADB(bfr[0], 0);
        LOADB(bfr[1], 1);
        STAGE(0); STAGE(1); STAGE(2);

#pragma unroll
        for (int jb = 0; jb < 12; jb++) {
            if (jb + 2 < 12) LOADB(bfr[(jb + 2) % 3], jb + 2);
            if (jb == 0)       asm volatile("s_waitcnt vmcnt(10)" ::: "memory");
            else if (jb == 10) asm volatile("s_waitcnt vmcnt(8)"  ::: "memory");
            else if (jb == 11) asm volatile("s_waitcnt vmcnt(0)"  ::: "memory");
            else               asm volatile("s_waitcnt vmcnt(16)" ::: "memory");
            __builtin_amdgcn_s_barrier();
            if (jb + 3 < 12) STAGE(jb + 3);    // target buf dead since jb-1
            int buf = jb & 3;

            Frag af[2][2];
#pragma unroll
            for (int mf = 0; mf < 2; mf++) {
                int r32 = mf * 16 + t;
#pragma unroll
                for (int c = 0; c < 2; c++) {
                    float4 f0 = *(const float4*)(&xs[buf][r32 * 256 + (((c * 8 + g * 2 + 0) ^ t) * 16)]);
                    float4 f1 = *(const float4*)(&xs[buf][r32 * 256 + (((c * 8 + g * 2 + 1) ^ t) * 16)]);
                    af[mf][c].u.x = cvt_pk(f0.x, f0.y);
                    af[mf][c].u.y = cvt_pk(f0.z, f0.w);
                    af[mf][c].u.z = cvt_pk(f1.x, f1.y);
                    af[mf][c].u.w = cvt_pk(f1.z, f1.w);
                }
            }
            __builtin_amdgcn_s_setprio(1);
#pragma unroll
            for (int j = 0; j < 3; j++)
#pragma unroll
                for (int c = 0; c < 2; c++) {
                    acc[j][0] = __builtin_amdgcn_mfma_f32_16x16x32_bf16(af[0][c].h, bfr[jb % 3][j * 2 + c].h, acc[j][0], 0, 0, 0);
                    acc[j][1] = __builtin_amdgcn_mfma_f32_16x16x32_bf16(af[1][c].h, bfr[jb % 3][j * 2 + c].h, acc[j][1], 0, 0, 0);
                }
            __builtin_amdgcn_s_setprio(0);
        }

#pragma unroll
        for (int j = 0; j < 3; j++) {
            int nb = w * 3 + j;
            int col = (nb & 3) * 16 + t;
#pragma unroll
            for (int mf = 0; mf < 2; mf++) {
                int row0 = m0 + mf * 16;
                if (nb < 8) {
                    unsigned short* dst = (nb < 4) ? qo : ko;
#pragma unroll
                    for (int r = 0; r < 4; r++)
                        dst[(size_t)(row0 + g * 4 + r) * HD_ + col] = f2bf(acc[j][mf][r]);
                } else {
                    int bb = m0 >> 11;
                    int trow = (row0 & 2047) + g * 4;
                    uint2 pkk;
                    pkk.x = cvt_pk(acc[j][mf][0], acc[j][mf][1]);
                    pkk.y = cvt_pk(acc[j][mf][2], acc[j][mf][3]);
                    *(uint2*)(vt + (((size_t)(bb * HD_ + col)) << 11) + trow) = pkk;
                }
            }
        }
    }
    grid_barrier(cnt + 32);

    // ================= Phase 2: causal flash attention =====================
    {
        int wv = tid >> 6, lane = tid & 63;
        int hi = lane >> 5, l31 = lane & 31;
        int b = blk & 7, idx = blk >> 3;                     // idx 0..63
        int qblk = (idx < 32) ? (63 - idx) : (idx - 32);     // heavy first
        int q0 = qblk * 32;
        int qg = q0 + l31;                                   // this lane's q row
        size_t bbase = (size_t)b * T_;
        int nt = qblk + 1;                                   // 32-key tiles
        int ks = wv;                                         // K-split
        int mt = (nt > ks) ? ((nt - ks + 3) >> 2) : 0;       // tiles for wave

        const unsigned short* kp = ko + bbase * HD_;
        const unsigned short* vp = vt + ((size_t)(b * HD_) << 11);
        char* KV = smem + wv * 16384;                        // wave-private

        Frag qf[4];
#pragma unroll
        for (int c = 0; c < 4; c++)
            qf[c].u = *(const uint4*)(qo + (bbase + qg) * HD_ + c * 16 + hi * 8);

        auto STAGE = [&](int j, int buf) {   // 4 K-chunks THEN 4 V-chunks
            int jj = (j < nt) ? j : (nt - 1);
            int kv0 = jj * 32;
#pragma unroll
            for (int q = 0; q < 4; q++) {    // K tile [32 keys][8 slots], ^= row&7
                int kr = q * 8 + (lane >> 3);
                int ka = (lane & 7) ^ (kr & 7);
                gl_lds16(kp + (size_t)(kv0 + kr) * HD_ + ka * 8, KV + buf * 4096 + q * 1024);
            }
#pragma unroll
            for (int q = 0; q < 4; q++) {    // V^T tile [64 d][4 slots], 3-term swz
                int vd = q * 16 + (lane >> 2);
                int va = (lane & 3) ^ (vd & 3) ^ ((vd >> 2) & 3);
                gl_lds16(vp + ((size_t)vd << 11) + kv0 + va * 8, KV + 8192 + buf * 4096 + q * 1024);
            }
        };

        f32x16 o0, o1;
#pragma unroll
        for (int r = 0; r < 16; r++) { o0[r] = 0.f; o1[r] = 0.f; }
        float lacc = 0.f;

        auto QK = [&](const char* KB, f32x16& st) {
#pragma unroll
            for (int r = 0; r < 16; r++) st[r] = 0.f;
            __builtin_amdgcn_s_setprio(1);
#pragma unroll
            for (int c = 0; c < 4; c++) {
                Frag ka;
                ka.u = *(const uint4*)(KB + l31 * 128 + (((c * 2 + hi) ^ (l31 & 7)) * 16));
                st = __builtin_amdgcn_mfma_f32_32x32x16_bf16(ka.h, qf[c].h, st, 0, 0, 0);
            }
            __builtin_amdgcn_s_setprio(0);
        };

        auto SMPV = [&](f32x16& st, int j, const char* VB) {
            int kv0 = j * 32;
            if (j == qblk) {           // diagonal tile: causal mask
#pragma unroll
                for (int r = 0; r < 16; r++) {
                    int key = kv0 + (r & 3) + 8 * (r >> 2) + 4 * hi;
                    if (key > qg) st[r] = -1e30f;
                }
            }
            float p[16], ss = 0.f;
#pragma unroll
            for (int r = 0; r < 16; r++) { p[r] = exp2f(st[r]); ss += p[r]; }
            lacc += ss;

            u32 A0 = cvt_pk(p[0], p[1]),   A1 = cvt_pk(p[2], p[3]);
            u32 B0 = cvt_pk(p[4], p[5]),   B1 = cvt_pk(p[6], p[7]);
            u32 C0 = cvt_pk(p[8], p[9]),   C1 = cvt_pk(p[10], p[11]);
            u32 D0 = cvt_pk(p[12], p[13]), D1 = cvt_pk(p[14], p[15]);
            u32 A0x = (u32)__shfl_xor((int)A0, 32);
            u32 A1x = (u32)__shfl_xor((int)A1, 32);
            u32 B0x = (u32)__shfl_xor((int)B0, 32);
            u32 B1x = (u32)__shfl_xor((int)B1, 32);
            u32 C0x = (u32)__shfl_xor((int)C0, 32);
            u32 C1x = (u32)__shfl_xor((int)C1, 32);
            u32 D0x = (u32)__shfl_xor((int)D0, 32);
            u32 D1x = (u32)__shfl_xor((int)D1, 32);
            Frag pf0, pf1;
            pf0.u.x = hi ? B0x : A0;
            pf0.u.y = hi ? B1x : A1;
            pf0.u.z = hi ? B0  : A0x;
            pf0.u.w = hi ? B1  : A1x;
            pf1.u.x = hi ? D0x : C0;
            pf1.u.y = hi ? D1x : C1;
            pf1.u.z = hi ? D0  : C0x;
            pf1.u.w = hi ? D1  : C1x;

            __builtin_amdgcn_s_setprio(1);
            {
                int sw0 = (l31 & 3) ^ ((l31 >> 2) & 3);
                Frag va;
                va.u = *(const uint4*)(VB + l31 * 64 + (((hi) ^ sw0) * 16));
                o0 = __builtin_amdgcn_mfma_f32_32x32x16_bf16(va.h, pf0.h, o0, 0, 0, 0);
                va.u = *(const uint4*)(VB + l31 * 64 + (((2 + hi) ^ sw0) * 16));
                o0 = __builtin_amdgcn_mfma_f32_32x32x16_bf16(va.h, pf1.h, o0, 0, 0, 0);
                int d1 = 32 + l31;
                int sw1 = (d1 & 3) ^ ((d1 >> 2) & 3);
                va.u = *(const uint4*)(VB + d1 * 64 + (((hi) ^ sw1) * 16));
                o1 = __builtin_amdgcn_mfma_f32_32x32x16_bf16(va.h, pf0.h, o1, 0, 0, 0);
                va.u = *(const uint4*)(VB + d1 * 64 + (((2 + hi) ^ sw1) * 16));
                o1 = __builtin_amdgcn_mfma_f32_32x32x16_bf16(va.h, pf1.h, o1, 0, 0, 0);
            }
            __builtin_amdgcn_s_setprio(0);
        };

        if (mt > 0) STAGE(ks, 0);
        if (mt > 1) STAGE(ks + 4, 1);

        int i = 0;
#pragma unroll 1
        for (; i + 2 <= mt; i += 2) {
            int ja = ks + 4 * i, jb2 = ja + 4;
            const char* KA = KV + (i & 1) * 4096;
            const char* VA = KV + 8192 + (i & 1) * 4096;
            const char* KB2 = KV + ((i + 1) & 1) * 4096;
            const char* VB2 = KV + 8192 + ((i + 1) & 1) * 4096;

            asm volatile("s_waitcnt vmcnt(12)" ::: "memory");   // K(a) ready
            f32x16 sa;
            QK(KA, sa);
            asm volatile("s_waitcnt vmcnt(4)" ::: "memory");    // V(a), K(b) ready
            f32x16 sb;
            QK(KB2, sb);          // overlaps softmax(a) (independent pipes)
            SMPV(sa, ja, VA);
            asm volatile("s_waitcnt vmcnt(0)" ::: "memory");    // V(b) ready
            if (i + 2 < mt) STAGE(ks + 4 * (i + 2), i & 1);
            SMPV(sb, jb2, VB2);
            if (i + 3 < mt) STAGE(ks + 4 * (i + 3), (i + 1) & 1);
        }
        if (i < mt) {   // odd tail: single tile, 8 outstanding at entry
            int ja = ks + 4 * i;
            const char* KA = KV + (i & 1) * 4096;
            const char* VA = KV + 8192 + (i & 1) * 4096;
            asm volatile("s_waitcnt vmcnt(4)" ::: "memory");    // K ready
            f32x16 sa;
            QK(KA, sa);
            asm volatile("s_waitcnt vmcnt(0)" ::: "memory");    // V ready
            SMPV(sa, ja, VA);
        }

        asm volatile("s_waitcnt vmcnt(0)" ::: "memory");   // drain before LDS reuse
        lacc += __shfl_xor(lacc, 32);
        __syncthreads();   // all waves done

        // ---- parallel 4-way merge ----
        float* MO = (float*)smem;
        {
            int base = (wv * 64 + lane) * 36;
#pragma unroll
            for (int qd = 0; qd < 4; qd++) {
                float4 w4;
                w4.x = o0[qd * 4 + 0]; w4.y = o0[qd * 4 + 1];
                w4.z = o0[qd * 4 + 2]; w4.w = o0[qd * 4 + 3];
                *(float4*)&MO[base + qd * 4] = w4;
                float4 v4;
                v4.x = o1[qd * 4 + 0]; v4.y = o1[qd * 4 + 1];
                v4.z = o1[qd * 4 + 2]; v4.w = o1[qd * 4 + 3];
                *(float4*)&MO[base + 16 + qd * 4] = v4;
            }
            MO[base + 32] = lacc;
        }
        __syncthreads();
        {
            int row = tid >> 3;                    // 0..31
            int c0 = (tid & 7) * 8;                // col base (multiple of 8)
            int j0 = 4 * ((c0 & 31) >> 3) + ((c0 >> 5) << 4);
            float lsum = 0.f;
#pragma unroll
            for (int k = 0; k < 4; k++) lsum += MO[(k * 64 + row) * 36 + 32];
            float inv = 1.0f / lsum;
            float4 aq = {0.f, 0.f, 0.f, 0.f};
            float4 bq = {0.f, 0.f, 0.f, 0.f};
#pragma unroll
            for (int k = 0; k < 4; k++) {
                float4 v0 = *(const float4*)&MO[(k * 64 + row) * 36 + j0];
                float4 v1 = *(const float4*)&MO[(k * 64 + row + 32) * 36 + j0];
                aq.x += v0.x; aq.y += v0.y; aq.z += v0.z; aq.w += v0.w;
                bq.x += v1.x; bq.y += v1.y; bq.z += v1.z; bq.w += v1.w;
            }
            aq.x *= inv; aq.y *= inv; aq.z *= inv; aq.w *= inv;
            bq.x *= inv; bq.y *= inv; bq.z *= inv; bq.w *= inv;
            float* op = out + (bbase + q0 + row) * HD_ + c0;
            *(float4*)&op[0] = aq;
            *(float4*)&op[4] = bq;
        }
    }
}

// ---------------------------------------------------------------------------
extern "C" void kernel_launch(void* const* d_in, const int* in_sizes, int n_in,
                              void* d_out, int out_size, void* d_ws, size_t ws_size,
                              hipStream_t stream) {
    const float* x  = (const float*)d_in[0];
    const float* Wq = (const float*)d_in[1];
    const float* Wk = (const float*)d_in[2];
    const float* Wv = (const float*)d_in[3];
    char* ws = (char*)d_ws;
    unsigned short* pkw = (unsigned short*)ws;                        // 294912 B
    unsigned short* qw = (unsigned short*)(ws + 294912);              // 2 MB
    unsigned short* kw = (unsigned short*)(ws + 294912 + 2097152);    // 2 MB
    unsigned short* vt = (unsigned short*)(ws + 294912 + 4194304);    // 2 MB
    unsigned* cnt = (unsigned*)(ws + 294912 + 6291456);               // 2 counters (256B)
    float* out = (float*)d_out;

    hipMemsetAsync(cnt, 0, 256, stream);
    hipLaunchKernelGGL(fused, dim3(NBLK), dim3(256), 0, stream,
                       x, Wq, Wk, Wv, pkw, qw, kw, vt, out, cnt);
}

// Round 20
// 41.618 us; speedup vs baseline: 3.7928x; 3.0592x over previous
//
#include <hip/hip_runtime.h>
#include <hip/hip_bf16.h>
#include <stdint.h>

#define B_  8
#define T_  2048
#define D_  768
#define HD_ 64
#define M_  (B_ * T_)   // 16384

typedef short s16x8 __attribute__((ext_vector_type(8)));
typedef float f32x4 __attribute__((ext_vector_type(4)));
typedef float f32x16 __attribute__((ext_vector_type(16)));
typedef unsigned int u32;

union Frag { uint4 u; s16x8 h; };

__device__ __forceinline__ unsigned short f2bf(float f) {
    unsigned u = __builtin_bit_cast(unsigned, f);
    u += 0x7FFFu + ((u >> 16) & 1u);            // RNE
    return (unsigned short)(u >> 16);
}
__device__ __forceinline__ unsigned pack_bf16x2(float lo, float hi) {
    return (unsigned)f2bf(lo) | ((unsigned)f2bf(hi) << 16);
}
// single-instruction packed f32x2 -> bf16x2 (RNE), gfx950
__device__ __forceinline__ unsigned cvt_pk(float lo, float hi) {
    unsigned r;
    asm("v_cvt_pk_bf16_f32 %0, %1, %2" : "=v"(r) : "v"(lo), "v"(hi));
    return r;
}

// async global -> LDS, 16B/lane; LDS dest must be the WAVE-UNIFORM base
// (hardware adds lane*16); global src is per-lane.
__device__ __forceinline__ void gl_lds16(const void* g, void* l) {
    __builtin_amdgcn_global_load_lds(
        (const __attribute__((address_space(1))) u32*)g,
        (__attribute__((address_space(3))) u32*)l, 16, 0, 0);
}

// ---------------------------------------------------------------------------
// Kernel 1: W packed into MFMA B-fragment order (16x16x32 layout for qkv).
// pk[((nb*24 + kk)*64 + lane)*8 + e] = W_mat[kk*32 + g*8 + e][(nb&3)*16 + t] * s
// ---------------------------------------------------------------------------
__global__ __launch_bounds__(64) void prep_pk(const float* __restrict__ Wq,
                                              const float* __restrict__ Wk,
                                              const float* __restrict__ Wv,
                                              unsigned short* __restrict__ pk) {
    int nb = blockIdx.x / 24, kk = blockIdx.x % 24;
    int lane = threadIdx.x, g = lane >> 4, t = lane & 15;
    int mat = nb >> 2, col = (nb & 3) * 16 + t;
    const float* W = (mat == 0) ? Wq : (mat == 1) ? Wk : Wv;
    float s = (mat == 0) ? 0.18033688011112042f : 1.0f;  // 0.125 * log2(e)
    float v[8];
#pragma unroll
    for (int e = 0; e < 8; e++)
        v[e] = W[(size_t)(kk * 32 + g * 8 + e) * HD_ + col] * s;
    uint4 u;
    u.x = pack_bf16x2(v[0], v[1]);
    u.y = pack_bf16x2(v[2], v[3]);
    u.z = pack_bf16x2(v[4], v[5]);
    u.w = pack_bf16x2(v[6], v[7]);
    *(uint4*)(pk + ((size_t)blockIdx.x * 64 + lane) * 8) = u;
}

// ---------------------------------------------------------------------------
// Kernel 2: QKV projection, BM=32 (single barrier per phase).  512 blocks
// (2/CU) x 256 thr (4 waves).  Waves split 12 n-blocks 3-apiece.
// x: 4-buf swizzled LDS DMA (3 stages ahead); STAGE(jb+3) issued right after
// the barrier (its target buf was fully read in phase jb-1 -> safe).
// B-frags: 3-set register rotation, 2 phases ahead, exact FIFO waits
// 10/16/../8/0 (queue order unchanged).  V written transposed vt[b][d][t].
// ---------------------------------------------------------------------------
__global__ __launch_bounds__(256, 2) void qkv_proj(const float* __restrict__ x,
                                                   const unsigned short* __restrict__ pk,
                                                   unsigned short* __restrict__ qo,
                                                   unsigned short* __restrict__ ko,
                                                   unsigned short* __restrict__ vt) {
    __shared__ char xs[4][8192];   // [buf][32 rows][16 slots of 16B], swizzled

    int tid = threadIdx.x, w = tid >> 6, lane = tid & 63;
    int g = lane >> 4, t = lane & 15;
    int m0 = blockIdx.x * 32;

    auto STAGE = [&](int jb) {
        int buf = jb & 3;
#pragma unroll
        for (int h = 0; h < 2; h++) {
            int s = tid + h * 256;                 // slot 0..511
            int row = s >> 4;
            int a = (s & 15) ^ (row & 15);
            gl_lds16(x + (size_t)(m0 + row) * D_ + jb * 64 + a * 4,
                     &xs[buf][(w * 64 + h * 256) * 16]);
        }
    };

    const unsigned short* wp = pk + (size_t)w * 36864;   // wave's 3 nb-blocks
    auto LOADB = [&](Frag (&bb)[6], int jb) {
#pragma unroll
        for (int j = 0; j < 3; j++)
#pragma unroll
            for (int c = 0; c < 2; c++)
                bb[j * 2 + c].u = *(const uint4*)(wp + ((size_t)(j * 24 + jb * 2 + c) * 64 + lane) * 8);
    };

    f32x4 acc[3][2];
#pragma unroll
    for (int j = 0; j < 3; j++)
#pragma unroll
        for (int mf = 0; mf < 2; mf++) acc[j][mf] = (f32x4){0.f, 0.f, 0.f, 0.f};

    Frag bfr[3][6];
    LOADB(bfr[0], 0);
    LOADB(bfr[1], 1);
    STAGE(0); STAGE(1); STAGE(2);

#pragma unroll
    for (int jb = 0; jb < 12; jb++) {
        if (jb + 2 < 12) LOADB(bfr[(jb + 2) % 3], jb + 2);
        if (jb == 0)       asm volatile("s_waitcnt vmcnt(10)" ::: "memory");
        else if (jb == 10) asm volatile("s_waitcnt vmcnt(8)"  ::: "memory");
        else if (jb == 11) asm volatile("s_waitcnt vmcnt(0)"  ::: "memory");
        else               asm volatile("s_waitcnt vmcnt(16)" ::: "memory");
        __builtin_amdgcn_s_barrier();
        if (jb + 3 < 12) STAGE(jb + 3);    // target buf dead since phase jb-1
        int buf = jb & 3;

        Frag af[2][2];
#pragma unroll
        for (int mf = 0; mf < 2; mf++) {
            int r32 = mf * 16 + t;
#pragma unroll
            for (int c = 0; c < 2; c++) {
                float4 f0 = *(const float4*)(&xs[buf][r32 * 256 + (((c * 8 + g * 2 + 0) ^ t) * 16)]);
                float4 f1 = *(const float4*)(&xs[buf][r32 * 256 + (((c * 8 + g * 2 + 1) ^ t) * 16)]);
                af[mf][c].u.x = cvt_pk(f0.x, f0.y);
                af[mf][c].u.y = cvt_pk(f0.z, f0.w);
                af[mf][c].u.z = cvt_pk(f1.x, f1.y);
                af[mf][c].u.w = cvt_pk(f1.z, f1.w);
            }
        }
        __builtin_amdgcn_s_setprio(1);
#pragma unroll
        for (int j = 0; j < 3; j++)
#pragma unroll
            for (int c = 0; c < 2; c++) {
                acc[j][0] = __builtin_amdgcn_mfma_f32_16x16x32_bf16(af[0][c].h, bfr[jb % 3][j * 2 + c].h, acc[j][0], 0, 0, 0);
                acc[j][1] = __builtin_amdgcn_mfma_f32_16x16x32_bf16(af[1][c].h, bfr[jb % 3][j * 2 + c].h, acc[j][1], 0, 0, 0);
            }
        __builtin_amdgcn_s_setprio(0);
    }

#pragma unroll
    for (int j = 0; j < 3; j++) {
        int nb = w * 3 + j;
        int col = (nb & 3) * 16 + t;
#pragma unroll
        for (int mf = 0; mf < 2; mf++) {
            int row0 = m0 + mf * 16;
            if (nb < 8) {
                unsigned short* dst = (nb < 4) ? qo : ko;
#pragma unroll
                for (int r = 0; r < 4; r++)
                    dst[(size_t)(row0 + g * 4 + r) * HD_ + col] = f2bf(acc[j][mf][r]);
            } else {
                int bb = m0 >> 11;
                int trow = (row0 & 2047) + g * 4;
                uint2 pkk;
                pkk.x = cvt_pk(acc[j][mf][0], acc[j][mf][1]);
                pkk.y = cvt_pk(acc[j][mf][2], acc[j][mf][3]);
                *(uint2*)(vt + (((size_t)(bb * HD_ + col)) << 11) + trow) = pkk;
            }
        }
    }
}

// ---------------------------------------------------------------------------
// Kernel 3: causal flash attention.  QBLK=32, 512 blocks (2/CU, heavy first)
// x 256 thr = 4 waves = 4-way K-split, wave-private 16KB LDS, barrier-free
// pairwise loop (waits 12/4/0), parallel 4-way merge epilogue.
// ---------------------------------------------------------------------------
__global__ __launch_bounds__(256) void attn(const unsigned short* __restrict__ qw,
                                            const unsigned short* __restrict__ kw,
                                            const unsigned short* __restrict__ vt,
                                            float* __restrict__ out) {
    __shared__ char smem[65536];   // wave wv: [K0|K1|V0|V1] x 4KB at wv*16384

    int tid = threadIdx.x, wv = tid >> 6, lane = tid & 63;
    int hi = lane >> 5, l31 = lane & 31;
    int blk = blockIdx.x;
    int b = blk & 7, idx = blk >> 3;                     // idx 0..63
    int qblk = (idx < 32) ? (63 - idx) : (idx - 32);     // heavy first
    int q0 = qblk * 32;
    int qg = q0 + l31;                                   // this lane's q row
    size_t bbase = (size_t)b * T_;
    int nt = qblk + 1;                                   // 32-key tiles
    int ks = wv;                                         // this wave's K-split
    int mt = (nt > ks) ? ((nt - ks + 3) >> 2) : 0;       // tiles for this wave

    const unsigned short* kp = kw + bbase * HD_;
    const unsigned short* vp = vt + ((size_t)(b * HD_) << 11);
    char* KV = smem + wv * 16384;                        // wave-private

    // Q B-frags (issued first -> oldest in the wave's vmcnt queue)
    Frag qf[4];
#pragma unroll
    for (int c = 0; c < 4; c++)
        qf[c].u = *(const uint4*)(qw + (bbase + qg) * HD_ + c * 16 + hi * 8);

    auto STAGE = [&](int j, int buf) {   // 4 K-chunks THEN 4 V-chunks (FIFO order)
        int jj = (j < nt) ? j : (nt - 1);
        int kv0 = jj * 32;
#pragma unroll
        for (int q = 0; q < 4; q++) {    // K tile [32 keys][8 slots], slot ^= row&7
            int kr = q * 8 + (lane >> 3);
            int ka = (lane & 7) ^ (kr & 7);
            gl_lds16(kp + (size_t)(kv0 + kr) * HD_ + ka * 8, KV + buf * 4096 + q * 1024);
        }
#pragma unroll
        for (int q = 0; q < 4; q++) {    // V^T tile [64 d][4 slots], 3-term swz
            int vd = q * 16 + (lane >> 2);
            int va = (lane & 3) ^ (vd & 3) ^ ((vd >> 2) & 3);
            gl_lds16(vp + ((size_t)vd << 11) + kv0 + va * 8, KV + 8192 + buf * 4096 + q * 1024);
        }
    };

    f32x16 o0, o1;
#pragma unroll
    for (int r = 0; r < 16; r++) { o0[r] = 0.f; o1[r] = 0.f; }
    float lacc = 0.f;

    // QK^T for one staged K tile -> st
    auto QK = [&](const char* KB, f32x16& st) {
#pragma unroll
        for (int r = 0; r < 16; r++) st[r] = 0.f;
        __builtin_amdgcn_s_setprio(1);
#pragma unroll
        for (int c = 0; c < 4; c++) {
            Frag ka;
            ka.u = *(const uint4*)(KB + l31 * 128 + (((c * 2 + hi) ^ (l31 & 7)) * 16));
            st = __builtin_amdgcn_mfma_f32_32x32x16_bf16(ka.h, qf[c].h, st, 0, 0, 0);
        }
        __builtin_amdgcn_s_setprio(0);
    };

    // mask + softmax + P-pack + PV for one tile
    auto SMPV = [&](f32x16& st, int j, const char* VB) {
        int kv0 = j * 32;
        if (j == qblk) {           // diagonal tile: causal mask
#pragma unroll
            for (int r = 0; r < 16; r++) {
                int key = kv0 + (r & 3) + 8 * (r >> 2) + 4 * hi;
                if (key > qg) st[r] = -1e30f;
            }
        }
        float p[16], ss = 0.f;
#pragma unroll
        for (int r = 0; r < 16; r++) { p[r] = exp2f(st[r]); ss += p[r]; }
        lacc += ss;

        // P (C/D layout) -> PV B-frags (r8-verified mapping).
        u32 A0 = cvt_pk(p[0], p[1]),   A1 = cvt_pk(p[2], p[3]);
        u32 B0 = cvt_pk(p[4], p[5]),   B1 = cvt_pk(p[6], p[7]);
        u32 C0 = cvt_pk(p[8], p[9]),   C1 = cvt_pk(p[10], p[11]);
        u32 D0 = cvt_pk(p[12], p[13]), D1 = cvt_pk(p[14], p[15]);
        u32 A0x = (u32)__shfl_xor((int)A0, 32);
        u32 A1x = (u32)__shfl_xor((int)A1, 32);
        u32 B0x = (u32)__shfl_xor((int)B0, 32);
        u32 B1x = (u32)__shfl_xor((int)B1, 32);
        u32 C0x = (u32)__shfl_xor((int)C0, 32);
        u32 C1x = (u32)__shfl_xor((int)C1, 32);
        u32 D0x = (u32)__shfl_xor((int)D0, 32);
        u32 D1x = (u32)__shfl_xor((int)D1, 32);
        Frag pf0, pf1;
        pf0.u.x = hi ? B0x : A0;
        pf0.u.y = hi ? B1x : A1;
        pf0.u.z = hi ? B0  : A0x;
        pf0.u.w = hi ? B1  : A1x;
        pf1.u.x = hi ? D0x : C0;
        pf1.u.y = hi ? D1x : C1;
        pf1.u.z = hi ? D0  : C0x;
        pf1.u.w = hi ? D1  : C1x;

        __builtin_amdgcn_s_setprio(1);
        {
            int sw0 = (l31 & 3) ^ ((l31 >> 2) & 3);
            Frag va;
            va.u = *(const uint4*)(VB + l31 * 64 + (((hi) ^ sw0) * 16));
            o0 = __builtin_amdgcn_mfma_f32_32x32x16_bf16(va.h, pf0.h, o0, 0, 0, 0);
            va.u = *(const uint4*)(VB + l31 * 64 + (((2 + hi) ^ sw0) * 16));
            o0 = __builtin_amdgcn_mfma_f32_32x32x16_bf16(va.h, pf1.h, o0, 0, 0, 0);
            int d1 = 32 + l31;
            int sw1 = (d1 & 3) ^ ((d1 >> 2) & 3);
            va.u = *(const uint4*)(VB + d1 * 64 + (((hi) ^ sw1) * 16));
            o1 = __builtin_amdgcn_mfma_f32_32x32x16_bf16(va.h, pf0.h, o1, 0, 0, 0);
            va.u = *(const uint4*)(VB + d1 * 64 + (((2 + hi) ^ sw1) * 16));
            o1 = __builtin_amdgcn_mfma_f32_32x32x16_bf16(va.h, pf1.h, o1, 0, 0, 0);
        }
        __builtin_amdgcn_s_setprio(0);
    };

    if (mt > 0) STAGE(ks, 0);
    if (mt > 1) STAGE(ks + 4, 1);

    int i = 0;
#pragma unroll 1
    for (; i + 2 <= mt; i += 2) {
        int ja = ks + 4 * i, jb2 = ja + 4;
        const char* KA = KV + (i & 1) * 4096;
        const char* VA = KV + 8192 + (i & 1) * 4096;
        const char* KB2 = KV + ((i + 1) & 1) * 4096;
        const char* VB2 = KV + 8192 + ((i + 1) & 1) * 4096;

        asm volatile("s_waitcnt vmcnt(12)" ::: "memory");   // K(a) ready
        f32x16 sa;
        QK(KA, sa);
        asm volatile("s_waitcnt vmcnt(4)" ::: "memory");    // V(a), K(b) ready
        f32x16 sb;
        QK(KB2, sb);          // overlaps softmax(a) below (independent pipes)
        SMPV(sa, ja, VA);
        asm volatile("s_waitcnt vmcnt(0)" ::: "memory");    // V(b) ready
        if (i + 2 < mt) STAGE(ks + 4 * (i + 2), i & 1);
        SMPV(sb, jb2, VB2);
        if (i + 3 < mt) STAGE(ks + 4 * (i + 3), (i + 1) & 1);
    }
    if (i < mt) {   // odd tail: single tile, 8 outstanding at entry
        int ja = ks + 4 * i;
        const char* KA = KV + (i & 1) * 4096;
        const char* VA = KV + 8192 + (i & 1) * 4096;
        asm volatile("s_waitcnt vmcnt(4)" ::: "memory");    // K ready
        f32x16 sa;
        QK(KA, sa);
        asm volatile("s_waitcnt vmcnt(0)" ::: "memory");    // V ready
        SMPV(sa, ja, VA);
    }

    asm volatile("s_waitcnt vmcnt(0)" ::: "memory");   // drain before LDS reuse
    lacc += __shfl_xor(lacc, 32);
    __syncthreads();   // all waves done

    // ---- parallel 4-way merge ----
    // store: MO[(wv*64 + lane)*36 + j], j = r for o0, 16+r for o1, 32 = lacc.
    float* MO = (float*)smem;
    {
        int base = (wv * 64 + lane) * 36;
#pragma unroll
        for (int qd = 0; qd < 4; qd++) {
            float4 w4;
            w4.x = o0[qd * 4 + 0]; w4.y = o0[qd * 4 + 1];
            w4.z = o0[qd * 4 + 2]; w4.w = o0[qd * 4 + 3];
            *(float4*)&MO[base + qd * 4] = w4;
            float4 v4;
            v4.x = o1[qd * 4 + 0]; v4.y = o1[qd * 4 + 1];
            v4.z = o1[qd * 4 + 2]; v4.w = o1[qd * 4 + 3];
            *(float4*)&MO[base + 16 + qd * 4] = v4;
        }
        MO[base + 32] = lacc;
    }
    __syncthreads();
    {
        int row = tid >> 3;                    // 0..31
        int c0 = (tid & 7) * 8;                // col base (multiple of 8)
        int j0 = 4 * ((c0 & 31) >> 3) + ((c0 >> 5) << 4);
        float lsum = 0.f;
#pragma unroll
        for (int k = 0; k < 4; k++) lsum += MO[(k * 64 + row) * 36 + 32];
        float inv = 1.0f / lsum;
        float4 aq = {0.f, 0.f, 0.f, 0.f};      // cols c0..c0+3   (hi=0 lanes)
        float4 bq = {0.f, 0.f, 0.f, 0.f};      // cols c0+4..c0+7 (hi=1 lanes)
#pragma unroll
        for (int k = 0; k < 4; k++) {
            float4 v0 = *(const float4*)&MO[(k * 64 + row) * 36 + j0];
            float4 v1 = *(const float4*)&MO[(k * 64 + row + 32) * 36 + j0];
            aq.x += v0.x; aq.y += v0.y; aq.z += v0.z; aq.w += v0.w;
            bq.x += v1.x; bq.y += v1.y; bq.z += v1.z; bq.w += v1.w;
        }
        aq.x *= inv; aq.y *= inv; aq.z *= inv; aq.w *= inv;
        bq.x *= inv; bq.y *= inv; bq.z *= inv; bq.w *= inv;
        float* op = out + (bbase + q0 + row) * HD_ + c0;
        *(float4*)&op[0] = aq;
        *(float4*)&op[4] = bq;
    }
}

// ---------------------------------------------------------------------------
extern "C" void kernel_launch(void* const* d_in, const int* in_sizes, int n_in,
                              void* d_out, int out_size, void* d_ws, size_t ws_size,
                              hipStream_t stream) {
    const float* x  = (const float*)d_in[0];
    const float* Wq = (const float*)d_in[1];
    const float* Wk = (const float*)d_in[2];
    const float* Wv = (const float*)d_in[3];
    char* ws = (char*)d_ws;
    unsigned short* pkw = (unsigned short*)ws;                        // 294912 B
    unsigned short* qw = (unsigned short*)(ws + 294912);              // 2 MB
    unsigned short* kw = (unsigned short*)(ws + 294912 + 2097152);    // 2 MB
    unsigned short* vt = (unsigned short*)(ws + 294912 + 4194304);    // 2 MB, [B][HD][T]
    float* out = (float*)d_out;

    hipLaunchKernelGGL(prep_pk, dim3(288), dim3(64), 0, stream, Wq, Wk, Wv, pkw);
    hipLaunchKernelGGL(qkv_proj, dim3(M_ / 32), dim3(256), 0, stream, x, pkw, qw, kw, vt);
    hipLaunchKernelGGL(attn, dim3(512), dim3(256), 0, stream, qw, kw, vt, out);
}